// Round 3
// baseline (3558.937 us; speedup 1.0000x reference)
//
#include <hip/hip_runtime.h>

#define N_NODES 50000
#define N_REL 16
#define D 128
#define K_AGG (N_REL * D)        // 2048
#define N_SEG (N_NODES * N_REL)  // 800000

typedef short bf16x8 __attribute__((ext_vector_type(8)));
typedef float f32x4 __attribute__((ext_vector_type(4)));
typedef unsigned short u16;
typedef unsigned int u32;

__device__ __forceinline__ u16 f32_to_bf16(float f) {
  u32 u = __builtin_bit_cast(u32, f);
  u32 r = (u + 0x7FFFu + ((u >> 16) & 1u)) >> 16;
  return (u16)r;
}
__device__ __forceinline__ float bf16_to_f32(u16 h) {
  u32 u = ((u32)h) << 16;
  return __builtin_bit_cast(float, u);
}

// ---------------- zero (uint4 grid-stride) ----------------
__global__ __launch_bounds__(256) void k_zero4(uint4* __restrict__ p, long long n4) {
  long long i = (long long)blockIdx.x * blockDim.x + threadIdx.x;
  long long stride = (long long)gridDim.x * blockDim.x;
  uint4 z; z.x = z.y = z.z = z.w = 0u;
  for (; i < n4; i += stride) p[i] = z;
}

// ---------------- per-(dst,rel) edge counts ----------------
__global__ __launch_bounds__(256) void k_count(const int* __restrict__ dst,
                                               const int* __restrict__ rel,
                                               int* __restrict__ cnt, int E) {
  int e = blockIdx.x * blockDim.x + threadIdx.x;
  if (e < E) atomicAdd(&cnt[dst[e] * N_REL + rel[e]], 1);
}

__global__ __launch_bounds__(256) void k_inv(const int* __restrict__ cnt,
                                             float* __restrict__ inv, int n) {
  int i = blockIdx.x * blockDim.x + threadIdx.x;
  if (i < n) inv[i] = cnt[i] > 0 ? 1.0f / (float)cnt[i] : 0.0f;
}

// ---------------- weight transpose+cast: W[r][d][h] (f32) -> Wt[h][r*128+d] (bf16) ----------------
__global__ __launch_bounds__(256) void k_transpose(const float* __restrict__ W,
                                                   u16* __restrict__ Wt, int nrel) {
  int idx = blockIdx.x * blockDim.x + threadIdx.x;
  int total = nrel * D * D;
  if (idx >= total) return;
  int h = idx & (D - 1);
  int rd = idx >> 7;  // r*128 + d
  Wt[(size_t)h * (nrel * D) + rd] = f32_to_bf16(W[idx]);
}

// ---------------- scatter (chunked): agg[(dst-c0)*16+rel][:] += x[src][:] * inv[seg] ----------------
// one wave (64 lanes) per edge, 2 dims per lane. BF=0: x is f32 (emb); BF=1: x is bf16 (x1).
template <int BF>
__global__ __launch_bounds__(256) void k_scatter(const int* __restrict__ src,
                                                 const int* __restrict__ dst,
                                                 const int* __restrict__ rel,
                                                 const float* __restrict__ xf,
                                                 const u16* __restrict__ xb,
                                                 const float* __restrict__ inv,
                                                 float* __restrict__ agg, int E,
                                                 int c0, int c1) {
  long long gid = (long long)blockIdx.x * blockDim.x + threadIdx.x;
  int e = (int)(gid >> 6);
  if (e >= E) return;
  int dn = dst[e];
  if (dn < c0 || dn >= c1) return;
  int lane = (int)(gid & 63);
  int r = rel[e];
  int seg = dn * N_REL + r;
  float sc = inv[seg];
  int s = src[e];
  float x0, x1v;
  if (BF) {
    u32 xv = *(const u32*)(xb + ((size_t)s << 7) + (lane << 1));
    x0 = bf16_to_f32((u16)(xv & 0xFFFFu));
    x1v = bf16_to_f32((u16)(xv >> 16));
  } else {
    float2 xv = *(const float2*)(xf + ((size_t)s << 7) + (lane << 1));
    x0 = xv.x;
    x1v = xv.y;
  }
  float* a = agg + (((size_t)(dn - c0) * N_REL + r) << 7) + (lane << 1);
  unsafeAtomicAdd(a, x0 * sc);
  unsafeAtomicAdd(a + 1, x1v * sc);
}

// ---------------- GEMM (chunked): out[n][h] = agg[n-c0][:]·Wt[h][:] + x[n][:]·rootT[h][:] + b[h] ----
// one wave computes a 16x128 output strip; MFMA 16x16x32 bf16, no LDS.
// L=1: x input f32 (emb), output bf16 (x1), ReLU. L=2: x input bf16 (x1), output f32 (d_out).
template <int L>
__global__ __launch_bounds__(256) void k_gemm(const float* __restrict__ agg,   // [NC, 2048] f32
                                              const float* __restrict__ xf,    // [N, 128] f32 (L=1)
                                              const u16* __restrict__ xb,      // [N, 128] bf16 (L=2)
                                              const u16* __restrict__ Wt,      // [128][2048] bf16
                                              const u16* __restrict__ rootT,   // [128][128] bf16
                                              const float* __restrict__ bias,  // [128] f32
                                              u16* __restrict__ outb,          // [N, 128] bf16 (L=1)
                                              float* __restrict__ outf,        // [N, 128] f32 (L=2)
                                              int c0, int c1) {
  int wave = (int)(((long long)blockIdx.x * blockDim.x + threadIdx.x) >> 6);
  int lane = threadIdx.x & 63;
  int node0 = c0 + (wave << 4);
  if (node0 >= c1) return;
  int m = lane & 15;   // A-row / B-col / C-col index
  int q = lane >> 4;   // k-subgroup (0..3)
  int row = node0 + m;

  f32x4 acc[8];
#pragma unroll
  for (int t = 0; t < 8; ++t)
#pragma unroll
    for (int i = 0; i < 4; ++i) acc[t][i] = 0.0f;

  const float* Arow = agg + (size_t)(row - c0) * K_AGG + (q << 3);

  for (int k0 = 0; k0 < K_AGG; k0 += 32) {
    const float4* ap = (const float4*)(Arow + k0);
    float4 a0 = ap[0];
    float4 a1 = ap[1];
    bf16x8 af;
    af[0] = (short)f32_to_bf16(a0.x); af[1] = (short)f32_to_bf16(a0.y);
    af[2] = (short)f32_to_bf16(a0.z); af[3] = (short)f32_to_bf16(a0.w);
    af[4] = (short)f32_to_bf16(a1.x); af[5] = (short)f32_to_bf16(a1.y);
    af[6] = (short)f32_to_bf16(a1.z); af[7] = (short)f32_to_bf16(a1.w);
#pragma unroll
    for (int t = 0; t < 8; ++t) {
      bf16x8 bf = *(const bf16x8*)(Wt + (size_t)(t * 16 + m) * K_AGG + k0 + (q << 3));
      acc[t] = __builtin_amdgcn_mfma_f32_16x16x32_bf16(af, bf, acc[t], 0, 0, 0);
    }
  }

  // root term: extra K=128 with A = x
#pragma unroll
  for (int k0 = 0; k0 < D; k0 += 32) {
    bf16x8 af;
    if (L == 1) {
      const float4* xp = (const float4*)(xf + (size_t)row * D + k0 + (q << 3));
      float4 a0 = xp[0];
      float4 a1 = xp[1];
      af[0] = (short)f32_to_bf16(a0.x); af[1] = (short)f32_to_bf16(a0.y);
      af[2] = (short)f32_to_bf16(a0.z); af[3] = (short)f32_to_bf16(a0.w);
      af[4] = (short)f32_to_bf16(a1.x); af[5] = (short)f32_to_bf16(a1.y);
      af[6] = (short)f32_to_bf16(a1.z); af[7] = (short)f32_to_bf16(a1.w);
    } else {
      af = *(const bf16x8*)(xb + (size_t)row * D + k0 + (q << 3));
    }
#pragma unroll
    for (int t = 0; t < 8; ++t) {
      bf16x8 bf = *(const bf16x8*)(rootT + (size_t)(t * 16 + m) * D + k0 + (q << 3));
      acc[t] = __builtin_amdgcn_mfma_f32_16x16x32_bf16(af, bf, acc[t], 0, 0, 0);
    }
  }

  // epilogue: C layout col=lane&15, row=(lane>>4)*4+reg  [m89]
#pragma unroll
  for (int t = 0; t < 8; ++t) {
    int h = t * 16 + m;
    float bv = bias[h];
#pragma unroll
    for (int r = 0; r < 4; ++r) {
      int rr = node0 + (q << 2) + r;
      float v = acc[t][r] + bv;
      if (L == 1) {
        v = v > 0.0f ? v : 0.0f;
        outb[(size_t)rr * D + h] = f32_to_bf16(v);
      } else {
        outf[(size_t)rr * D + h] = v;
      }
    }
  }
}

extern "C" void kernel_launch(void* const* d_in, const int* in_sizes, int n_in,
                              void* d_out, int out_size, void* d_ws, size_t ws_size,
                              hipStream_t stream) {
  const int* edge_index = (const int*)d_in[0];
  const int* edge_type  = (const int*)d_in[1];
  const float* emb   = (const float*)d_in[2];
  const float* W1    = (const float*)d_in[3];
  const float* root1 = (const float*)d_in[4];
  const float* b1    = (const float*)d_in[5];
  const float* W2    = (const float*)d_in[6];
  const float* root2 = (const float*)d_in[7];
  const float* b2    = (const float*)d_in[8];
  float* out = (float*)d_out;

  int E = in_sizes[0] / 2;
  const int* src = edge_index;      // row 0
  const int* dst = edge_index + E;  // row 1

  char* ws = (char*)d_ws;
  size_t off = 0;
  auto take = [&](size_t bytes) -> char* {
    char* p = ws + off;
    off += (bytes + 255) & ~(size_t)255;
    return p;
  };
  int*   cnt = (int*)take((size_t)N_SEG * 4);
  float* inv = (float*)take((size_t)N_SEG * 4);
  u16*   x1  = (u16*)take((size_t)N_NODES * D * 2);   // layer-1 activations, bf16
  u16*   Wt1 = (u16*)take((size_t)K_AGG * D * 2);
  u16*   rT1 = (u16*)take((size_t)D * D * 2);
  u16*   Wt2 = (u16*)take((size_t)K_AGG * D * 2);
  u16*   rT2 = (u16*)take((size_t)D * D * 2);

  // agg chunk buffer: whatever workspace remains (NC nodes x 16 rel x 128 f32)
  float* agg = (float*)(ws + off);
  size_t avail = (ws_size > off) ? (ws_size - off) : 0;
  long long perNode = (long long)N_REL * D * sizeof(float);  // 8192 B
  long long ncap = (long long)(avail / (size_t)perNode);
  int NC = (ncap >= N_NODES) ? N_NODES : (int)((ncap / 64) * 64);
  if (NC <= 0) NC = 64;  // degenerate safeguard
  int nchunks = (N_NODES + NC - 1) / NC;

  int cntBlocks = (E + 255) / 256;
  long long scatterThreads = (long long)E * 64;
  int scatterBlocks = (int)((scatterThreads + 255) / 256);

  // --- prep (counts + transposed bf16 weights shared by both layers) ---
  k_zero4<<<2048, 256, 0, stream>>>((uint4*)cnt, (long long)N_SEG * 4 / 16);
  k_count<<<cntBlocks, 256, 0, stream>>>(dst, edge_type, cnt, E);
  k_inv<<<(N_SEG + 255) / 256, 256, 0, stream>>>(cnt, inv, N_SEG);
  k_transpose<<<(N_REL * D * D + 255) / 256, 256, 0, stream>>>(W1, Wt1, N_REL);
  k_transpose<<<(D * D + 255) / 256, 256, 0, stream>>>(root1, rT1, 1);
  k_transpose<<<(N_REL * D * D + 255) / 256, 256, 0, stream>>>(W2, Wt2, N_REL);
  k_transpose<<<(D * D + 255) / 256, 256, 0, stream>>>(root2, rT2, 1);

  for (int layer = 0; layer < 2; ++layer) {
    for (int c = 0; c < nchunks; ++c) {
      int c0 = c * NC;
      int c1 = c0 + NC;
      if (c1 > N_NODES) c1 = N_NODES;
      long long aggN4 = ((long long)(c1 - c0) * K_AGG * 4) / 16;
      k_zero4<<<8192, 256, 0, stream>>>((uint4*)agg, aggN4);
      int waves = (c1 - c0) / 16;  // chunk sizes are multiples of 16
      int gblocks = (waves + 3) / 4;
      if (layer == 0) {
        k_scatter<0><<<scatterBlocks, 256, 0, stream>>>(src, dst, edge_type, emb,
                                                        nullptr, inv, agg, E, c0, c1);
        k_gemm<1><<<gblocks, 256, 0, stream>>>(agg, emb, nullptr, Wt1, rT1, b1,
                                               x1, nullptr, c0, c1);
      } else {
        k_scatter<1><<<scatterBlocks, 256, 0, stream>>>(src, dst, edge_type, nullptr,
                                                        x1, inv, agg, E, c0, c1);
        k_gemm<2><<<gblocks, 256, 0, stream>>>(agg, nullptr, x1, Wt2, rT2, b2,
                                               nullptr, out, c0, c1);
      }
    }
  }
}

// Round 4
// 1311.583 us; speedup vs baseline: 2.7135x; 2.7135x over previous
//
#include <hip/hip_runtime.h>

#define N_NODES 50000
#define N_REL 16
#define D 128
#define K_AGG (N_REL * D)        // 2048
#define N_SEG (N_NODES * N_REL)  // 800000

typedef short bf16x8 __attribute__((ext_vector_type(8)));
typedef float f32x4 __attribute__((ext_vector_type(4)));
typedef unsigned short u16;
typedef unsigned int u32;

__device__ __forceinline__ u16 f32_to_bf16(float f) {
  u32 u = __builtin_bit_cast(u32, f);
  u32 r = (u + 0x7FFFu + ((u >> 16) & 1u)) >> 16;
  return (u16)r;
}
__device__ __forceinline__ float bf16_to_f32(u16 h) {
  u32 u = ((u32)h) << 16;
  return __builtin_bit_cast(float, u);
}

// ---------------- zero (uint4 grid-stride) ----------------
__global__ __launch_bounds__(256) void k_zero4(uint4* __restrict__ p, long long n4) {
  long long i = (long long)blockIdx.x * blockDim.x + threadIdx.x;
  long long stride = (long long)gridDim.x * blockDim.x;
  uint4 z; z.x = z.y = z.z = z.w = 0u;
  for (; i < n4; i += stride) p[i] = z;
}

// ---------------- f32 -> bf16 convert (x4 per thread) ----------------
__global__ __launch_bounds__(256) void k_cvt(const float* __restrict__ in,
                                             u16* __restrict__ out, long long n4) {
  long long i = (long long)blockIdx.x * blockDim.x + threadIdx.x;
  if (i >= n4) return;
  float4 v = ((const float4*)in)[i];
  u32 p0 = (u32)f32_to_bf16(v.x) | ((u32)f32_to_bf16(v.y) << 16);
  u32 p1 = (u32)f32_to_bf16(v.z) | ((u32)f32_to_bf16(v.w) << 16);
  ((u32*)out)[i * 2] = p0;
  ((u32*)out)[i * 2 + 1] = p1;
}

// ---------------- per-(dst,rel) edge counts ----------------
__global__ __launch_bounds__(256) void k_count(const int* __restrict__ dst,
                                               const int* __restrict__ rel,
                                               int* __restrict__ cnt, int E) {
  int e = blockIdx.x * blockDim.x + threadIdx.x;
  if (e < E) atomicAdd(&cnt[dst[e] * N_REL + rel[e]], 1);
}

// ---------------- scan: per-block sums ----------------
__global__ __launch_bounds__(256) void k_bsum(const int* __restrict__ cnt,
                                              int* __restrict__ bsum, int n) {
  __shared__ int sm[256];
  int i = blockIdx.x * 256 + threadIdx.x;
  int v = (i < n) ? cnt[i] : 0;
  sm[threadIdx.x] = v;
  __syncthreads();
  for (int s = 128; s > 0; s >>= 1) {
    if (threadIdx.x < s) sm[threadIdx.x] += sm[threadIdx.x + s];
    __syncthreads();
  }
  if (threadIdx.x == 0) bsum[blockIdx.x] = sm[0];
}

// ---------------- scan: single-block exclusive scan of block sums ----------------
__global__ __launch_bounds__(1024) void k_bscan(int* __restrict__ bsum, int nb) {
  __shared__ int sm[1024];
  __shared__ int carry;
  if (threadIdx.x == 0) carry = 0;
  __syncthreads();
  int niter = (nb + 1023) / 1024;
  for (int it = 0; it < niter; ++it) {
    int i = it * 1024 + threadIdx.x;
    int v = (i < nb) ? bsum[i] : 0;
    sm[threadIdx.x] = v;
    __syncthreads();
    for (int s = 1; s < 1024; s <<= 1) {
      int t = (threadIdx.x >= s) ? sm[threadIdx.x - s] : 0;
      __syncthreads();
      sm[threadIdx.x] += t;
      __syncthreads();
    }
    int incl = sm[threadIdx.x];
    int c = carry;
    __syncthreads();
    if (i < nb) bsum[i] = c + incl - v;
    if (threadIdx.x == 1023) carry = c + sm[1023];
    __syncthreads();
  }
}

// ---------------- scan: per-element exclusive offsets ----------------
__global__ __launch_bounds__(256) void k_off(const int* __restrict__ cnt,
                                             const int* __restrict__ bsum,
                                             int* __restrict__ off, int n) {
  __shared__ int sm[256];
  int i = blockIdx.x * 256 + threadIdx.x;
  int v = (i < n) ? cnt[i] : 0;
  sm[threadIdx.x] = v;
  __syncthreads();
  for (int s = 1; s < 256; s <<= 1) {
    int t = (threadIdx.x >= s) ? sm[threadIdx.x - s] : 0;
    __syncthreads();
    sm[threadIdx.x] += t;
    __syncthreads();
  }
  int excl = sm[threadIdx.x] - v + bsum[blockIdx.x];
  if (i < n) off[i] = excl;
  if (i == n - 1) off[n] = excl + v;
}

// ---------------- CSR fill: bucket[off[seg]+k] = src ----------------
__global__ __launch_bounds__(256) void k_fill(const int* __restrict__ src,
                                              const int* __restrict__ dst,
                                              const int* __restrict__ rel,
                                              const int* __restrict__ off,
                                              int* __restrict__ cur,
                                              int* __restrict__ bucket, int E) {
  int e = blockIdx.x * blockDim.x + threadIdx.x;
  if (e >= E) return;
  int seg = dst[e] * N_REL + rel[e];
  int p = off[seg] + atomicAdd(&cur[seg], 1);
  bucket[p] = src[e];
}

// ---------------- aggregation: one wave per segment, write bf16 agg once ----------------
__global__ __launch_bounds__(256) void k_agg(const int* __restrict__ off,
                                             const int* __restrict__ bucket,
                                             const u16* __restrict__ x,   // [N,128] bf16
                                             u16* __restrict__ agg,       // [nseg,128] bf16
                                             int seg0, int seg1) {
  long long gid = (long long)blockIdx.x * blockDim.x + threadIdx.x;
  int w = (int)(gid >> 6);
  int lane = (int)(gid & 63);
  int seg = seg0 + w;
  if (seg >= seg1) return;
  int o0 = off[seg], o1 = off[seg + 1];
  float s0 = 0.0f, s1 = 0.0f;
  for (int i = o0; i < o1; ++i) {
    int s = bucket[i];
    u32 xv = *(const u32*)(x + ((size_t)s << 7) + (lane << 1));
    s0 += bf16_to_f32((u16)(xv & 0xFFFFu));
    s1 += bf16_to_f32((u16)(xv >> 16));
  }
  float sc = (o1 > o0) ? 1.0f / (float)(o1 - o0) : 0.0f;
  u32 p = (u32)f32_to_bf16(s0 * sc) | ((u32)f32_to_bf16(s1 * sc) << 16);
  *(u32*)(agg + (((size_t)(seg - seg0)) << 7) + (lane << 1)) = p;
}

// ---------------- GEMM: out[n][:] = agg[n][:]·Wt + x[n][:]·rootT + b ----------------
// one wave per 16x128 output strip; MFMA 16x16x32 bf16, no LDS.
// L=1: output bf16 (x1) + ReLU. L=2: output f32 (d_out).
template <int L>
__global__ __launch_bounds__(256) void k_gemm(const u16* __restrict__ agg,    // [NC,2048] bf16
                                              const u16* __restrict__ x,      // [N,128] bf16
                                              const u16* __restrict__ Wt,     // [128][2048] bf16
                                              const u16* __restrict__ rootT,  // [128][128] bf16
                                              const float* __restrict__ bias, // [128] f32
                                              u16* __restrict__ outb,
                                              float* __restrict__ outf,
                                              int c0, int c1) {
  int wave = (int)(((long long)blockIdx.x * blockDim.x + threadIdx.x) >> 6);
  int lane = threadIdx.x & 63;
  int node0 = c0 + (wave << 4);
  if (node0 >= c1) return;
  int m = lane & 15;   // A-row / B-col index
  int q = lane >> 4;   // k-subgroup (0..3)
  int row = node0 + m;

  f32x4 acc[8];
#pragma unroll
  for (int t = 0; t < 8; ++t)
#pragma unroll
    for (int i = 0; i < 4; ++i) acc[t][i] = 0.0f;

  const u16* Arow = agg + (size_t)(row - c0) * K_AGG + (q << 3);

  for (int k0 = 0; k0 < K_AGG; k0 += 32) {
    bf16x8 af = *(const bf16x8*)(Arow + k0);
#pragma unroll
    for (int t = 0; t < 8; ++t) {
      bf16x8 bf = *(const bf16x8*)(Wt + (size_t)(t * 16 + m) * K_AGG + k0 + (q << 3));
      acc[t] = __builtin_amdgcn_mfma_f32_16x16x32_bf16(af, bf, acc[t], 0, 0, 0);
    }
  }

  // root term: extra K=128 with A = x (bf16)
#pragma unroll
  for (int k0 = 0; k0 < D; k0 += 32) {
    bf16x8 af = *(const bf16x8*)(x + (size_t)row * D + k0 + (q << 3));
#pragma unroll
    for (int t = 0; t < 8; ++t) {
      bf16x8 bf = *(const bf16x8*)(rootT + (size_t)(t * 16 + m) * D + k0 + (q << 3));
      acc[t] = __builtin_amdgcn_mfma_f32_16x16x32_bf16(af, bf, acc[t], 0, 0, 0);
    }
  }

  // epilogue: C layout col=lane&15, row=(lane>>4)*4+reg  [m89]
#pragma unroll
  for (int t = 0; t < 8; ++t) {
    int h = t * 16 + m;
    float bv = bias[h];
#pragma unroll
    for (int r = 0; r < 4; ++r) {
      int rr = node0 + (q << 2) + r;
      float v = acc[t][r] + bv;
      if (L == 1) {
        v = v > 0.0f ? v : 0.0f;
        outb[(size_t)rr * D + h] = f32_to_bf16(v);
      } else {
        outf[(size_t)rr * D + h] = v;
      }
    }
  }
}

// ---------------- weight transpose+cast: W[r][d][h] (f32) -> Wt[h][r*128+d] (bf16) ----------------
__global__ __launch_bounds__(256) void k_transpose(const float* __restrict__ W,
                                                   u16* __restrict__ Wt, int nrel) {
  int idx = blockIdx.x * blockDim.x + threadIdx.x;
  int total = nrel * D * D;
  if (idx >= total) return;
  int h = idx & (D - 1);
  int rd = idx >> 7;  // r*128 + d
  Wt[(size_t)h * (nrel * D) + rd] = f32_to_bf16(W[idx]);
}

extern "C" void kernel_launch(void* const* d_in, const int* in_sizes, int n_in,
                              void* d_out, int out_size, void* d_ws, size_t ws_size,
                              hipStream_t stream) {
  const int* edge_index = (const int*)d_in[0];
  const int* edge_type  = (const int*)d_in[1];
  const float* emb   = (const float*)d_in[2];
  const float* W1    = (const float*)d_in[3];
  const float* root1 = (const float*)d_in[4];
  const float* b1    = (const float*)d_in[5];
  const float* W2    = (const float*)d_in[6];
  const float* root2 = (const float*)d_in[7];
  const float* b2    = (const float*)d_in[8];
  float* out = (float*)d_out;

  int E = in_sizes[0] / 2;
  const int* src = edge_index;      // row 0
  const int* dst = edge_index + E;  // row 1
  int nblocks_seg = (N_SEG + 255) / 256;  // 3125

  char* ws = (char*)d_ws;
  size_t off_b = 0;
  auto take = [&](size_t bytes) -> char* {
    char* p = ws + off_b;
    off_b += (bytes + 255) & ~(size_t)255;
    return p;
  };
  int*   cnt    = (int*)take((size_t)N_SEG * 4);
  int*   cur    = (int*)take((size_t)N_SEG * 4);          // zeroed together with cnt
  int*   offs   = (int*)take((size_t)(N_SEG + 1) * 4);
  int*   bsum   = (int*)take((size_t)nblocks_seg * 4);
  int*   bucket = (int*)take((size_t)2000000 * 4);        // >= E
  u16*   embb   = (u16*)take((size_t)N_NODES * D * 2);    // emb as bf16
  u16*   x1     = (u16*)take((size_t)N_NODES * D * 2);    // layer-1 activations bf16
  u16*   Wt1    = (u16*)take((size_t)K_AGG * D * 2);
  u16*   rT1    = (u16*)take((size_t)D * D * 2);
  u16*   Wt2    = (u16*)take((size_t)K_AGG * D * 2);
  u16*   rT2    = (u16*)take((size_t)D * D * 2);

  // agg chunk buffer in remaining ws: NC nodes x 16 rel x 128 bf16 (4 KB/node)
  u16* agg = (u16*)(ws + off_b);
  size_t avail = (ws_size > off_b) ? (ws_size - off_b) : 0;
  long long ncap = (long long)(avail / 4096);
  int NC = (ncap >= N_NODES) ? N_NODES : (int)((ncap / 64) * 64);
  if (NC <= 0) NC = 64;
  int nchunks = (N_NODES + NC - 1) / NC;

  int eBlocks = (E + 255) / 256;

  // --- CSR build (shared by both layers) ---
  k_zero4<<<512, 256, 0, stream>>>((uint4*)cnt, (long long)N_SEG * 8 / 16);  // cnt+cur
  k_count<<<eBlocks, 256, 0, stream>>>(dst, edge_type, cnt, E);
  k_bsum<<<nblocks_seg, 256, 0, stream>>>(cnt, bsum, N_SEG);
  k_bscan<<<1, 1024, 0, stream>>>(bsum, nblocks_seg);
  k_off<<<nblocks_seg, 256, 0, stream>>>(cnt, bsum, offs, N_SEG);
  k_fill<<<eBlocks, 256, 0, stream>>>(src, dst, edge_type, offs, cur, bucket, E);

  // --- weight prep ---
  k_cvt<<<((N_NODES * D / 4) + 255) / 256, 256, 0, stream>>>(emb, embb,
                                                             (long long)N_NODES * D / 4);
  k_transpose<<<(N_REL * D * D + 255) / 256, 256, 0, stream>>>(W1, Wt1, N_REL);
  k_transpose<<<(D * D + 255) / 256, 256, 0, stream>>>(root1, rT1, 1);
  k_transpose<<<(N_REL * D * D + 255) / 256, 256, 0, stream>>>(W2, Wt2, N_REL);
  k_transpose<<<(D * D + 255) / 256, 256, 0, stream>>>(root2, rT2, 1);

  for (int layer = 0; layer < 2; ++layer) {
    const u16* xin = (layer == 0) ? embb : x1;
    const u16* Wt  = (layer == 0) ? Wt1 : Wt2;
    const u16* rT  = (layer == 0) ? rT1 : rT2;
    const float* bb = (layer == 0) ? b1 : b2;
    for (int c = 0; c < nchunks; ++c) {
      int c0 = c * NC;
      int c1 = c0 + NC;
      if (c1 > N_NODES) c1 = N_NODES;
      int seg0 = c0 * N_REL, seg1 = c1 * N_REL;
      int aggBlocks = ((seg1 - seg0) + 3) / 4;  // 1 wave/segment, 4 waves/block
      k_agg<<<aggBlocks, 256, 0, stream>>>(offs, bucket, xin, agg, seg0, seg1);
      int waves = (c1 - c0 + 15) / 16;
      int gblocks = (waves + 3) / 4;
      if (layer == 0) {
        k_gemm<1><<<gblocks, 256, 0, stream>>>(agg, xin, Wt, rT, bb, x1, nullptr, c0, c1);
      } else {
        k_gemm<2><<<gblocks, 256, 0, stream>>>(agg, xin, Wt, rT, bb, nullptr, out, c0, c1);
      }
    }
  }
}

// Round 7
// 1220.936 us; speedup vs baseline: 2.9149x; 1.0742x over previous
//
#include <hip/hip_runtime.h>

#define N_NODES 50000
#define N_REL 16
#define D 128
#define N_SEG (N_NODES * N_REL)  // 800000

typedef short bf16x8 __attribute__((ext_vector_type(8)));
typedef float f32x4 __attribute__((ext_vector_type(4)));
typedef unsigned short u16;
typedef unsigned int u32;

__device__ __forceinline__ u16 f32_to_bf16(float f) {
  u32 u = __builtin_bit_cast(u32, f);
  u32 r = (u + 0x7FFFu + ((u >> 16) & 1u)) >> 16;
  return (u16)r;
}
__device__ __forceinline__ float bf16_to_f32(u16 h) {
  u32 u = ((u32)h) << 16;
  return __builtin_bit_cast(float, u);
}

// ---------------- zero (uint4 grid-stride) ----------------
__global__ __launch_bounds__(256) void k_zero4(uint4* __restrict__ p, long long n4) {
  long long i = (long long)blockIdx.x * blockDim.x + threadIdx.x;
  long long stride = (long long)gridDim.x * blockDim.x;
  uint4 z; z.x = z.y = z.z = z.w = 0u;
  for (; i < n4; i += stride) p[i] = z;
}

// ---------------- f32 -> bf16 convert (x4 per thread) ----------------
__global__ __launch_bounds__(256) void k_cvt(const float* __restrict__ in,
                                             u16* __restrict__ out, long long n4) {
  long long i = (long long)blockIdx.x * blockDim.x + threadIdx.x;
  if (i >= n4) return;
  float4 v = ((const float4*)in)[i];
  u32 p0 = (u32)f32_to_bf16(v.x) | ((u32)f32_to_bf16(v.y) << 16);
  u32 p1 = (u32)f32_to_bf16(v.z) | ((u32)f32_to_bf16(v.w) << 16);
  ((u32*)out)[i * 2] = p0;
  ((u32*)out)[i * 2 + 1] = p1;
}

// ---------------- per-(dst,rel) edge counts ----------------
__global__ __launch_bounds__(256) void k_count(const int* __restrict__ dst,
                                               const int* __restrict__ rel,
                                               int* __restrict__ cnt, int E) {
  int e = blockIdx.x * blockDim.x + threadIdx.x;
  if (e < E) atomicAdd(&cnt[dst[e] * N_REL + rel[e]], 1);
}

// ---------------- scan: per-block sums ----------------
__global__ __launch_bounds__(256) void k_bsum(const int* __restrict__ cnt,
                                              int* __restrict__ bsum, int n) {
  __shared__ int sm[256];
  int i = blockIdx.x * 256 + threadIdx.x;
  int v = (i < n) ? cnt[i] : 0;
  sm[threadIdx.x] = v;
  __syncthreads();
  for (int s = 128; s > 0; s >>= 1) {
    if (threadIdx.x < s) sm[threadIdx.x] += sm[threadIdx.x + s];
    __syncthreads();
  }
  if (threadIdx.x == 0) bsum[blockIdx.x] = sm[0];
}

// ---------------- scan: single-block exclusive scan of block sums ----------------
__global__ __launch_bounds__(1024) void k_bscan(int* __restrict__ bsum, int nb) {
  __shared__ int sm[1024];
  __shared__ int carry;
  if (threadIdx.x == 0) carry = 0;
  __syncthreads();
  int niter = (nb + 1023) / 1024;
  for (int it = 0; it < niter; ++it) {
    int i = it * 1024 + threadIdx.x;
    int v = (i < nb) ? bsum[i] : 0;
    sm[threadIdx.x] = v;
    __syncthreads();
    for (int s = 1; s < 1024; s <<= 1) {
      int t = (threadIdx.x >= s) ? sm[threadIdx.x - s] : 0;
      __syncthreads();
      sm[threadIdx.x] += t;
      __syncthreads();
    }
    int incl = sm[threadIdx.x];
    int c = carry;
    __syncthreads();
    if (i < nb) bsum[i] = c + incl - v;
    if (threadIdx.x == 1023) carry = c + sm[1023];
    __syncthreads();
  }
}

// ---------------- scan: per-element exclusive offsets ----------------
__global__ __launch_bounds__(256) void k_off(const int* __restrict__ cnt,
                                             const int* __restrict__ bsum,
                                             int* __restrict__ off, int n) {
  __shared__ int sm[256];
  int i = blockIdx.x * 256 + threadIdx.x;
  int v = (i < n) ? cnt[i] : 0;
  sm[threadIdx.x] = v;
  __syncthreads();
  for (int s = 1; s < 256; s <<= 1) {
    int t = (threadIdx.x >= s) ? sm[threadIdx.x - s] : 0;
    __syncthreads();
    sm[threadIdx.x] += t;
    __syncthreads();
  }
  int excl = sm[threadIdx.x] - v + bsum[blockIdx.x];
  if (i < n) off[i] = excl;
  if (i == n - 1) off[n] = excl + v;
}

// ---------------- CSR fill (countdown — cnt is dead after k_off) ----------------
__global__ __launch_bounds__(256) void k_fill(const int* __restrict__ src,
                                              const int* __restrict__ dst,
                                              const int* __restrict__ rel,
                                              const int* __restrict__ off,
                                              int* __restrict__ cnt,
                                              int* __restrict__ bucket, int E) {
  int e = blockIdx.x * blockDim.x + threadIdx.x;
  if (e >= E) return;
  int seg = dst[e] * N_REL + rel[e];
  int old = atomicSub(&cnt[seg], 1);          // old in [1, cnt]
  bucket[off[seg] + old - 1] = src[e];
}

// ---------------- aggregation: one wave per segment, write bf16 agg row once ----------------
__global__ __launch_bounds__(256) void k_agg(const int* __restrict__ off,
                                             const int* __restrict__ bucket,
                                             const u16* __restrict__ x,   // [N,128] bf16
                                             u16* __restrict__ agg,       // chunk, bf16
                                             int seg0, int seg1) {
  long long gid = (long long)blockIdx.x * blockDim.x + threadIdx.x;
  int seg = seg0 + (int)(gid >> 6);
  int lane = (int)(gid & 63);
  if (seg >= seg1) return;
  int o0 = off[seg], o1 = off[seg + 1];
  float s0 = 0.0f, s1 = 0.0f;
  for (int i = o0; i < o1; ++i) {
    int s = bucket[i];
    u32 xv = *(const u32*)(x + ((size_t)s << 7) + (lane << 1));
    s0 += bf16_to_f32((u16)(xv & 0xFFFFu));
    s1 += bf16_to_f32((u16)(xv >> 16));
  }
  float sc = (o1 > o0) ? 1.0f / (float)(o1 - o0) : 0.0f;
  u32 p = (u32)f32_to_bf16(s0 * sc) | ((u32)f32_to_bf16(s1 * sc) << 16);
  *(u32*)(agg + ((size_t)(seg - seg0) << 7) + (lane << 1)) = p;
}

// ---------------- weight -> MFMA-fragment-linear bf16 ----------------
// Wf[(kb*8+t)*512 + lane*8 + j] = Bmat[k = kb*32 + (lane>>4)*8 + j][h = t*16 + (lane&15)]
// Bmat[k][h] = W[k>>7][k&127][h]  (root: nkb=4 -> k<128 -> r=0)
__global__ __launch_bounds__(256) void k_wfrag(const float* __restrict__ W,
                                               u16* __restrict__ Wf, int nkb) {
  int tid = blockIdx.x * blockDim.x + threadIdx.x;
  int total = nkb * 8 * 64;
  if (tid >= total) return;
  int lane = tid & 63;
  int t = (tid >> 6) & 7;
  int kb = tid >> 9;
  int h = t * 16 + (lane & 15);
  int kbase = kb * 32 + ((lane >> 4) << 3);
  bf16x8 frag;
#pragma unroll
  for (int j = 0; j < 8; ++j) {
    int k = kbase + j;
    frag[j] = (short)f32_to_bf16(W[(size_t)(k >> 7) * (D * D) + (size_t)(k & 127) * D + h]);
  }
  *(bf16x8*)(Wf + (size_t)tid * 8) = frag;   // tid*8 u16 = 16B aligned
}

// ---------------- split-K GEMM over a node chunk: C[n][h] += agg-slice · W-slice -----------
// block = 4 waves = 4 K-splits of one 32-node M-tile; B fragment-linear (1KB loads);
// f32 atomic accumulate into C. agg rows local to chunk [c0, c1).
__global__ __launch_bounds__(256) void k_gemmW(const u16* __restrict__ agg,  // [(c1-c0)+16][16][128]
                                               const u16* __restrict__ Wf,   // frag-linear, 64 kb
                                               float* __restrict__ C,        // [N][128] f32
                                               int c0, int c1) {
  int ks = threadIdx.x >> 6;   // K-split 0..3 (512 k each)
  int lane = threadIdx.x & 63;
  int node0 = c0 + blockIdx.x * 32;
  if (node0 >= c1) return;
  int m = lane & 15;
  int q = lane >> 4;

  f32x4 acc[2][8];
#pragma unroll
  for (int s = 0; s < 2; ++s)
#pragma unroll
    for (int t = 0; t < 8; ++t)
#pragma unroll
      for (int i = 0; i < 4; ++i) acc[s][t][i] = 0.0f;

  for (int i = 0; i < 16; ++i) {
    int kb = ks * 16 + i;              // k-block of 32
    int r = kb >> 2;                   // relation
    int doff = ((kb & 3) << 5) + (q << 3);
    const u16* a0p = agg + (((size_t)(node0 - c0 + m) << 4) + r) * D + doff;
    bf16x8 a0 = *(const bf16x8*)a0p;
    bf16x8 a1 = *(const bf16x8*)(a0p + 16 * N_REL * D);  // +16 nodes (slack rows cover tail)
    const u16* bp = Wf + ((size_t)kb << 12) + ((size_t)lane << 3);
#pragma unroll
    for (int t = 0; t < 8; ++t) {
      bf16x8 b = *(const bf16x8*)(bp + t * 512);
      acc[0][t] = __builtin_amdgcn_mfma_f32_16x16x32_bf16(a0, b, acc[0][t], 0, 0, 0);
      acc[1][t] = __builtin_amdgcn_mfma_f32_16x16x32_bf16(a1, b, acc[1][t], 0, 0, 0);
    }
  }

  // C layout: col=lane&15, row=(lane>>4)*4+reg  [m89]
#pragma unroll
  for (int s = 0; s < 2; ++s) {
#pragma unroll
    for (int t = 0; t < 8; ++t) {
      int h = t * 16 + m;
#pragma unroll
      for (int r4 = 0; r4 < 4; ++r4) {
        int node = node0 + s * 16 + (q << 2) + r4;
        if (node < c1) unsafeAtomicAdd(&C[(size_t)node * D + h], acc[s][t][r4]);
      }
    }
  }
}

// ---------------- root GEMM: C[n][h] += sum_k x[n][k] * root[k][h] (K=128, atomic) --------
__global__ __launch_bounds__(256) void k_root(const u16* __restrict__ x,   // [N,128] bf16
                                              const u16* __restrict__ Rf,  // frag-linear, 4 kb
                                              float* __restrict__ C) {
  long long gid = (long long)blockIdx.x * blockDim.x + threadIdx.x;
  int wave = (int)(gid >> 6);
  int lane = (int)(gid & 63);
  int node0 = wave << 4;
  if (node0 >= N_NODES) return;
  int m = lane & 15;
  int q = lane >> 4;

  f32x4 acc[8];
#pragma unroll
  for (int t = 0; t < 8; ++t)
#pragma unroll
    for (int i = 0; i < 4; ++i) acc[t][i] = 0.0f;

#pragma unroll
  for (int kb = 0; kb < 4; ++kb) {
    bf16x8 a = *(const bf16x8*)(x + (size_t)(node0 + m) * D + (kb << 5) + (q << 3));
    const u16* bp = Rf + ((size_t)kb << 12) + ((size_t)lane << 3);
#pragma unroll
    for (int t = 0; t < 8; ++t) {
      bf16x8 b = *(const bf16x8*)(bp + t * 512);
      acc[t] = __builtin_amdgcn_mfma_f32_16x16x32_bf16(a, b, acc[t], 0, 0, 0);
    }
  }
#pragma unroll
  for (int t = 0; t < 8; ++t) {
    int h = t * 16 + m;
#pragma unroll
    for (int r4 = 0; r4 < 4; ++r4) {
      int node = node0 + (q << 2) + r4;
      unsafeAtomicAdd(&C[(size_t)node * D + h], acc[t][r4]);
    }
  }
}

// ---------------- epilogue: bias (+relu) + cast ----------------
template <int L>
__global__ __launch_bounds__(256) void k_post(const float* __restrict__ C,
                                              const float* __restrict__ bias,
                                              u16* __restrict__ outb,
                                              float* __restrict__ outf, long long n4) {
  long long i = (long long)blockIdx.x * blockDim.x + threadIdx.x;
  if (i >= n4) return;
  float4 c = ((const float4*)C)[i];
  int h = (int)((i << 2) & (D - 1));
  float4 bv = *(const float4*)(bias + h);
  float v0 = c.x + bv.x, v1 = c.y + bv.y, v2 = c.z + bv.z, v3 = c.w + bv.w;
  if (L == 1) {
    v0 = v0 > 0.0f ? v0 : 0.0f;
    v1 = v1 > 0.0f ? v1 : 0.0f;
    v2 = v2 > 0.0f ? v2 : 0.0f;
    v3 = v3 > 0.0f ? v3 : 0.0f;
    u32 p0 = (u32)f32_to_bf16(v0) | ((u32)f32_to_bf16(v1) << 16);
    u32 p1 = (u32)f32_to_bf16(v2) | ((u32)f32_to_bf16(v3) << 16);
    ((u32*)outb)[i * 2] = p0;
    ((u32*)outb)[i * 2 + 1] = p1;
  } else {
    float4 o; o.x = v0; o.y = v1; o.z = v2; o.w = v3;
    ((float4*)outf)[i] = o;
  }
}

extern "C" void kernel_launch(void* const* d_in, const int* in_sizes, int n_in,
                              void* d_out, int out_size, void* d_ws, size_t ws_size,
                              hipStream_t stream) {
  const int* edge_index = (const int*)d_in[0];
  const int* edge_type  = (const int*)d_in[1];
  const float* emb   = (const float*)d_in[2];
  const float* W1    = (const float*)d_in[3];
  const float* root1 = (const float*)d_in[4];
  const float* b1    = (const float*)d_in[5];
  const float* W2    = (const float*)d_in[6];
  const float* root2 = (const float*)d_in[7];
  const float* b2    = (const float*)d_in[8];
  float* out = (float*)d_out;

  int E = in_sizes[0] / 2;
  const int* src = edge_index;      // row 0
  const int* dst = edge_index + E;  // row 1
  int nblocks_seg = (N_SEG + 255) / 256;  // 3125

  char* ws = (char*)d_ws;
  size_t off_b = 0;
  auto take = [&](size_t bytes) -> char* {
    char* p = ws + off_b;
    off_b += (bytes + 255) & ~(size_t)255;
    return p;
  };
  int*   cnt    = (int*)take((size_t)N_SEG * 4);
  int*   offs   = (int*)take((size_t)(N_SEG + 1) * 4);
  int*   bsum   = (int*)take((size_t)nblocks_seg * 4);
  int*   bucket = (int*)take((size_t)E * 4);
  u16*   embb   = (u16*)take((size_t)N_NODES * D * 2);
  u16*   x1     = (u16*)take((size_t)N_NODES * D * 2);
  u16*   Wf1    = (u16*)take((size_t)64 * 8 * 512 * 2);
  u16*   Rf1    = (u16*)take((size_t)4 * 8 * 512 * 2);
  u16*   Wf2    = (u16*)take((size_t)64 * 8 * 512 * 2);
  u16*   Rf2    = (u16*)take((size_t)4 * 8 * 512 * 2);
  float* C      = (float*)take((size_t)N_NODES * D * 4);   // 25.6 MB f32 accumulator

  // agg chunk buffer: adaptive to remaining ws. NC nodes (mult of 32) + 16 slack
  // node-rows (second M-strip tail reads). 4 KB per node-row.
  u16* agg = (u16*)(ws + off_b);
  size_t avail = (ws_size > off_b) ? (ws_size - off_b) : 0;
  long long ncap = (long long)(avail / 4096) - 16;   // reserve slack rows
  int NC = (ncap >= N_NODES) ? N_NODES : (int)((ncap / 32) * 32);
  if (NC <= 0) NC = 32;  // degenerate safeguard
  int nchunks = (N_NODES + NC - 1) / NC;

  int eBlocks = (E + 255) / 256;
  int rootBlocks = (N_NODES / 16 + 3) / 4;
  long long cN4 = (long long)N_NODES * D / 4;
  int postBlocks = (int)((cN4 + 255) / 256);

  // --- CSR build (shared by both layers) ---
  k_zero4<<<512, 256, 0, stream>>>((uint4*)cnt, (long long)N_SEG * 4 / 16);
  k_count<<<eBlocks, 256, 0, stream>>>(dst, edge_type, cnt, E);
  k_bsum<<<nblocks_seg, 256, 0, stream>>>(cnt, bsum, N_SEG);
  k_bscan<<<1, 1024, 0, stream>>>(bsum, nblocks_seg);
  k_off<<<nblocks_seg, 256, 0, stream>>>(cnt, bsum, offs, N_SEG);
  k_fill<<<eBlocks, 256, 0, stream>>>(src, dst, edge_type, offs, cnt, bucket, E);

  // --- weight prep ---
  k_cvt<<<((N_NODES * D / 4) + 255) / 256, 256, 0, stream>>>(emb, embb,
                                                             (long long)N_NODES * D / 4);
  k_wfrag<<<(64 * 8 * 64 + 255) / 256, 256, 0, stream>>>(W1, Wf1, 64);
  k_wfrag<<<(4 * 8 * 64 + 255) / 256, 256, 0, stream>>>(root1, Rf1, 4);
  k_wfrag<<<(64 * 8 * 64 + 255) / 256, 256, 0, stream>>>(W2, Wf2, 64);
  k_wfrag<<<(4 * 8 * 64 + 255) / 256, 256, 0, stream>>>(root2, Rf2, 4);

  for (int layer = 0; layer < 2; ++layer) {
    const u16* xin = (layer == 0) ? embb : x1;
    const u16* Wf  = (layer == 0) ? Wf1 : Wf2;
    const u16* Rf  = (layer == 0) ? Rf1 : Rf2;
    const float* bb = (layer == 0) ? b1 : b2;

    k_zero4<<<2048, 256, 0, stream>>>((uint4*)C, (long long)N_NODES * D * 4 / 16);
    for (int c = 0; c < nchunks; ++c) {
      int c0 = c * NC;
      int c1 = c0 + NC;
      if (c1 > N_NODES) c1 = N_NODES;
      int segs = (c1 - c0) * N_REL;
      int aggBlocks = (segs + 3) / 4;              // 1 wave/segment
      int gBlocks = (c1 - c0 + 31) / 32;           // 1 block / 32-node M-tile
      k_agg<<<aggBlocks, 256, 0, stream>>>(offs, bucket, xin, agg,
                                           c0 * N_REL, c1 * N_REL);
      k_gemmW<<<gBlocks, 256, 0, stream>>>(agg, Wf, C, c0, c1);
    }
    k_root<<<rootBlocks, 256, 0, stream>>>(xin, Rf, C);
    if (layer == 0) {
      k_post<1><<<postBlocks, 256, 0, stream>>>(C, bb, x1, nullptr, cN4);
    } else {
      k_post<2><<<postBlocks, 256, 0, stream>>>(C, bb, nullptr, out, cN4);
    }
  }
}

// Round 8
// 575.469 us; speedup vs baseline: 6.1844x; 2.1216x over previous
//
#include <hip/hip_runtime.h>

#define N_NODES 50000
#define N_REL 16
#define D 128
#define N_SEG (N_NODES * N_REL)  // 800000

typedef short bf16x8 __attribute__((ext_vector_type(8)));
typedef float f32x4 __attribute__((ext_vector_type(4)));
typedef unsigned short u16;
typedef unsigned int u32;

__device__ __forceinline__ u16 f32_to_bf16(float f) {
  u32 u = __builtin_bit_cast(u32, f);
  u32 r = (u + 0x7FFFu + ((u >> 16) & 1u)) >> 16;
  return (u16)r;
}
__device__ __forceinline__ float bf16_to_f32(u16 h) {
  u32 u = ((u32)h) << 16;
  return __builtin_bit_cast(float, u);
}

// ---------------- zero (uint4 grid-stride) ----------------
__global__ __launch_bounds__(256) void k_zero4(uint4* __restrict__ p, long long n4) {
  long long i = (long long)blockIdx.x * blockDim.x + threadIdx.x;
  long long stride = (long long)gridDim.x * blockDim.x;
  uint4 z; z.x = z.y = z.z = z.w = 0u;
  for (; i < n4; i += stride) p[i] = z;
}

// ---------------- f32 -> bf16 convert (x4 per thread) ----------------
__global__ __launch_bounds__(256) void k_cvt(const float* __restrict__ in,
                                             u16* __restrict__ out, long long n4) {
  long long i = (long long)blockIdx.x * blockDim.x + threadIdx.x;
  if (i >= n4) return;
  float4 v = ((const float4*)in)[i];
  u32 p0 = (u32)f32_to_bf16(v.x) | ((u32)f32_to_bf16(v.y) << 16);
  u32 p1 = (u32)f32_to_bf16(v.z) | ((u32)f32_to_bf16(v.w) << 16);
  ((u32*)out)[i * 2] = p0;
  ((u32*)out)[i * 2 + 1] = p1;
}

// ---------------- per-(dst,rel) edge counts ----------------
__global__ __launch_bounds__(256) void k_count(const int* __restrict__ dst,
                                               const int* __restrict__ rel,
                                               int* __restrict__ cnt, int E) {
  int e = blockIdx.x * blockDim.x + threadIdx.x;
  if (e < E) atomicAdd(&cnt[dst[e] * N_REL + rel[e]], 1);
}

// ---------------- scan: per-block sums ----------------
__global__ __launch_bounds__(256) void k_bsum(const int* __restrict__ cnt,
                                              int* __restrict__ bsum, int n) {
  __shared__ int sm[256];
  int i = blockIdx.x * 256 + threadIdx.x;
  int v = (i < n) ? cnt[i] : 0;
  sm[threadIdx.x] = v;
  __syncthreads();
  for (int s = 128; s > 0; s >>= 1) {
    if (threadIdx.x < s) sm[threadIdx.x] += sm[threadIdx.x + s];
    __syncthreads();
  }
  if (threadIdx.x == 0) bsum[blockIdx.x] = sm[0];
}

// ---------------- scan: single-block exclusive scan of block sums ----------------
__global__ __launch_bounds__(1024) void k_bscan(int* __restrict__ bsum, int nb) {
  __shared__ int sm[1024];
  __shared__ int carry;
  if (threadIdx.x == 0) carry = 0;
  __syncthreads();
  int niter = (nb + 1023) / 1024;
  for (int it = 0; it < niter; ++it) {
    int i = it * 1024 + threadIdx.x;
    int v = (i < nb) ? bsum[i] : 0;
    sm[threadIdx.x] = v;
    __syncthreads();
    for (int s = 1; s < 1024; s <<= 1) {
      int t = (threadIdx.x >= s) ? sm[threadIdx.x - s] : 0;
      __syncthreads();
      sm[threadIdx.x] += t;
      __syncthreads();
    }
    int incl = sm[threadIdx.x];
    int c = carry;
    __syncthreads();
    if (i < nb) bsum[i] = c + incl - v;
    if (threadIdx.x == 1023) carry = c + sm[1023];
    __syncthreads();
  }
}

// ---------------- scan: per-element exclusive offsets ----------------
__global__ __launch_bounds__(256) void k_off(const int* __restrict__ cnt,
                                             const int* __restrict__ bsum,
                                             int* __restrict__ off, int n) {
  __shared__ int sm[256];
  int i = blockIdx.x * 256 + threadIdx.x;
  int v = (i < n) ? cnt[i] : 0;
  sm[threadIdx.x] = v;
  __syncthreads();
  for (int s = 1; s < 256; s <<= 1) {
    int t = (threadIdx.x >= s) ? sm[threadIdx.x - s] : 0;
    __syncthreads();
    sm[threadIdx.x] += t;
    __syncthreads();
  }
  int excl = sm[threadIdx.x] - v + bsum[blockIdx.x];
  if (i < n) off[i] = excl;
  if (i == n - 1) off[n] = excl + v;
}

// ---------------- CSR fill (countdown — cnt is dead after k_off) ----------------
__global__ __launch_bounds__(256) void k_fill(const int* __restrict__ src,
                                              const int* __restrict__ dst,
                                              const int* __restrict__ rel,
                                              const int* __restrict__ off,
                                              int* __restrict__ cnt,
                                              int* __restrict__ bucket, int E) {
  int e = blockIdx.x * blockDim.x + threadIdx.x;
  if (e >= E) return;
  int seg = dst[e] * N_REL + rel[e];
  int old = atomicSub(&cnt[seg], 1);          // old in [1, cnt]
  bucket[off[seg] + old - 1] = src[e];
}

// ---------------- weight -> MFMA-fragment-linear bf16 ----------------
// Wf[(kb*8+t)*512 + lane*8 + j] = Bmat[k = kb*32 + (lane>>4)*8 + j][h = t*16 + (lane&15)]
// Bmat[k][h] = W[k>>7][k&127][h]  (root: nkb=4 -> k<128 -> r=0)
__global__ __launch_bounds__(256) void k_wfrag(const float* __restrict__ W,
                                               u16* __restrict__ Wf, int nkb) {
  int tid = blockIdx.x * blockDim.x + threadIdx.x;
  int total = nkb * 8 * 64;
  if (tid >= total) return;
  int lane = tid & 63;
  int t = (tid >> 6) & 7;
  int kb = tid >> 9;
  int h = t * 16 + (lane & 15);
  int kbase = kb * 32 + ((lane >> 4) << 3);
  bf16x8 frag;
#pragma unroll
  for (int j = 0; j < 8; ++j) {
    int k = kbase + j;
    frag[j] = (short)f32_to_bf16(W[(size_t)(k >> 7) * (D * D) + (size_t)(k & 127) * D + h]);
  }
  *(bf16x8*)(Wf + (size_t)tid * 8) = frag;   // tid*8 u16 = 16B aligned
}

// ---------------- fully fused RGCN layer ----------------
// One wave = 16-node M-tile. For each relation r: lane (m=lane&15, q=lane>>4)
// gather-means segment (node0+m, r) straight into MFMA A-fragment registers
// (f32, dims kb*32+q*8..+7), then 4x8 MFMAs vs frag-linear W_r accumulate the
// C-tile. Root term via direct x loads + Rf. Bias (+ReLU) + store fused.
// No agg buffer, no C buffer, no atomics.
template <int L>  // L=1: bf16 out + ReLU; L=2: f32 out
__global__ __launch_bounds__(256) void k_layer(const int* __restrict__ off,
                                               const int* __restrict__ bucket,
                                               const u16* __restrict__ x,    // [N,128] bf16
                                               const u16* __restrict__ Wf,   // 64 kb frag-linear
                                               const u16* __restrict__ Rf,   // 4 kb frag-linear
                                               const float* __restrict__ bias,
                                               u16* __restrict__ outb,
                                               float* __restrict__ outf) {
  int wave = blockIdx.x * 4 + (threadIdx.x >> 6);
  int lane = threadIdx.x & 63;
  int node0 = wave << 4;
  if (node0 >= N_NODES) return;        // 50000 = 3125*16, exact
  int m = lane & 15;
  int q = lane >> 4;
  int node = node0 + m;                // A-row this lane serves

  f32x4 acc[8];
#pragma unroll
  for (int t = 0; t < 8; ++t)
#pragma unroll
    for (int i = 0; i < 4; ++i) acc[t][i] = 0.0f;

  // ---- root term: A = x[node][.] direct bf16 ----
  {
    const u16* xp = x + ((size_t)node << 7) + (q << 3);
#pragma unroll
    for (int kb = 0; kb < 4; ++kb) {
      bf16x8 a = *(const bf16x8*)(xp + kb * 32);
      const u16* bp = Rf + ((size_t)kb << 12) + ((size_t)lane << 3);
#pragma unroll
      for (int t = 0; t < 8; ++t) {
        bf16x8 b = *(const bf16x8*)(bp + t * 512);
        acc[t] = __builtin_amdgcn_mfma_f32_16x16x32_bf16(a, b, acc[t], 0, 0, 0);
      }
    }
  }

  // ---- 16 relations: gather-mean into A-frag regs, MFMA vs W_r ----
  for (int r = 0; r < N_REL; ++r) {
    int seg = (node << 4) + r;
    int o0 = off[seg];
    int o1 = off[seg + 1];

    float a0[8], a1[8], a2[8], a3[8];
#pragma unroll
    for (int j = 0; j < 8; ++j) { a0[j] = 0.f; a1[j] = 0.f; a2[j] = 0.f; a3[j] = 0.f; }

    for (int i = o0; i < o1; ++i) {    // divergent across m-quads; exec-masked
      int s = bucket[i];
      const u16* xs = x + ((size_t)s << 7) + (q << 3);
      bf16x8 v0 = *(const bf16x8*)(xs);
      bf16x8 v1 = *(const bf16x8*)(xs + 32);
      bf16x8 v2 = *(const bf16x8*)(xs + 64);
      bf16x8 v3 = *(const bf16x8*)(xs + 96);
#pragma unroll
      for (int j = 0; j < 8; ++j) {
        a0[j] += bf16_to_f32((u16)v0[j]);
        a1[j] += bf16_to_f32((u16)v1[j]);
        a2[j] += bf16_to_f32((u16)v2[j]);
        a3[j] += bf16_to_f32((u16)v3[j]);
      }
    }

    float sc = (o1 > o0) ? 1.0f / (float)(o1 - o0) : 0.0f;
    bf16x8 f0, f1, f2, f3;
#pragma unroll
    for (int j = 0; j < 8; ++j) {
      f0[j] = (short)f32_to_bf16(a0[j] * sc);
      f1[j] = (short)f32_to_bf16(a1[j] * sc);
      f2[j] = (short)f32_to_bf16(a2[j] * sc);
      f3[j] = (short)f32_to_bf16(a3[j] * sc);
    }

    const u16* bp = Wf + ((size_t)(r * 4) << 12) + ((size_t)lane << 3);
#pragma unroll
    for (int t = 0; t < 8; ++t) {
      bf16x8 b0 = *(const bf16x8*)(bp + t * 512);
      bf16x8 b1 = *(const bf16x8*)(bp + 4096 + t * 512);
      bf16x8 b2 = *(const bf16x8*)(bp + 8192 + t * 512);
      bf16x8 b3 = *(const bf16x8*)(bp + 12288 + t * 512);
      acc[t] = __builtin_amdgcn_mfma_f32_16x16x32_bf16(f0, b0, acc[t], 0, 0, 0);
      acc[t] = __builtin_amdgcn_mfma_f32_16x16x32_bf16(f1, b1, acc[t], 0, 0, 0);
      acc[t] = __builtin_amdgcn_mfma_f32_16x16x32_bf16(f2, b2, acc[t], 0, 0, 0);
      acc[t] = __builtin_amdgcn_mfma_f32_16x16x32_bf16(f3, b3, acc[t], 0, 0, 0);
    }
  }

  // ---- epilogue: C layout col=lane&15, row=(lane>>4)*4+reg [m89] ----
#pragma unroll
  for (int t = 0; t < 8; ++t) {
    int h = t * 16 + m;
    float bv = bias[h];
#pragma unroll
    for (int r4 = 0; r4 < 4; ++r4) {
      int n = node0 + (q << 2) + r4;
      float v = acc[t][r4] + bv;
      if (L == 1) {
        v = v > 0.0f ? v : 0.0f;
        outb[(size_t)n * D + h] = f32_to_bf16(v);
      } else {
        outf[(size_t)n * D + h] = v;
      }
    }
  }
}

extern "C" void kernel_launch(void* const* d_in, const int* in_sizes, int n_in,
                              void* d_out, int out_size, void* d_ws, size_t ws_size,
                              hipStream_t stream) {
  const int* edge_index = (const int*)d_in[0];
  const int* edge_type  = (const int*)d_in[1];
  const float* emb   = (const float*)d_in[2];
  const float* W1    = (const float*)d_in[3];
  const float* root1 = (const float*)d_in[4];
  const float* b1    = (const float*)d_in[5];
  const float* W2    = (const float*)d_in[6];
  const float* root2 = (const float*)d_in[7];
  const float* b2    = (const float*)d_in[8];
  float* out = (float*)d_out;

  int E = in_sizes[0] / 2;
  const int* src = edge_index;      // row 0
  const int* dst = edge_index + E;  // row 1
  int nblocks_seg = (N_SEG + 255) / 256;  // 3125

  char* ws = (char*)d_ws;
  size_t off_b = 0;
  auto take = [&](size_t bytes) -> char* {
    char* p = ws + off_b;
    off_b += (bytes + 255) & ~(size_t)255;
    return p;
  };
  int*   cnt    = (int*)take((size_t)N_SEG * 4);
  int*   offs   = (int*)take((size_t)(N_SEG + 1) * 4);
  int*   bsum   = (int*)take((size_t)nblocks_seg * 4);
  int*   bucket = (int*)take((size_t)E * 4);
  u16*   embb   = (u16*)take((size_t)N_NODES * D * 2);
  u16*   x1     = (u16*)take((size_t)N_NODES * D * 2);
  u16*   Wf1    = (u16*)take((size_t)64 * 8 * 512 * 2);
  u16*   Rf1    = (u16*)take((size_t)4 * 8 * 512 * 2);
  u16*   Wf2    = (u16*)take((size_t)64 * 8 * 512 * 2);
  u16*   Rf2    = (u16*)take((size_t)4 * 8 * 512 * 2);
  // total ~41 MB — no chunking needed

  int eBlocks = (E + 255) / 256;
  int layerBlocks = (N_NODES / 16 + 3) / 4;  // 3125 waves -> 782 blocks

  // --- CSR build (shared by both layers) ---
  k_zero4<<<512, 256, 0, stream>>>((uint4*)cnt, (long long)N_SEG * 4 / 16);
  k_count<<<eBlocks, 256, 0, stream>>>(dst, edge_type, cnt, E);
  k_bsum<<<nblocks_seg, 256, 0, stream>>>(cnt, bsum, N_SEG);
  k_bscan<<<1, 1024, 0, stream>>>(bsum, nblocks_seg);
  k_off<<<nblocks_seg, 256, 0, stream>>>(cnt, bsum, offs, N_SEG);
  k_fill<<<eBlocks, 256, 0, stream>>>(src, dst, edge_type, offs, cnt, bucket, E);

  // --- weight prep ---
  k_cvt<<<((N_NODES * D / 4) + 255) / 256, 256, 0, stream>>>(emb, embb,
                                                             (long long)N_NODES * D / 4);
  k_wfrag<<<(64 * 8 * 64 + 255) / 256, 256, 0, stream>>>(W1, Wf1, 64);
  k_wfrag<<<(4 * 8 * 64 + 255) / 256, 256, 0, stream>>>(root1, Rf1, 4);
  k_wfrag<<<(64 * 8 * 64 + 255) / 256, 256, 0, stream>>>(W2, Wf2, 64);
  k_wfrag<<<(4 * 8 * 64 + 255) / 256, 256, 0, stream>>>(root2, Rf2, 4);

  // --- two fused layers ---
  k_layer<1><<<layerBlocks, 256, 0, stream>>>(offs, bucket, embb, Wf1, Rf1, b1,
                                              x1, nullptr);
  k_layer<2><<<layerBlocks, 256, 0, stream>>>(offs, bucket, x1, Wf2, Rf2, b2,
                                              nullptr, out);
}

// Round 9
// 548.050 us; speedup vs baseline: 6.4938x; 1.0500x over previous
//
#include <hip/hip_runtime.h>

#define N_NODES 50000
#define N_REL 16
#define D 128
#define N_SEG (N_NODES * N_REL)  // 800000

typedef short bf16x8 __attribute__((ext_vector_type(8)));
typedef float f32x4 __attribute__((ext_vector_type(4)));
typedef unsigned short u16;
typedef unsigned int u32;

__device__ __forceinline__ u16 f32_to_bf16(float f) {
  u32 u = __builtin_bit_cast(u32, f);
  u32 r = (u + 0x7FFFu + ((u >> 16) & 1u)) >> 16;
  return (u16)r;
}
__device__ __forceinline__ float bf16_to_f32(u16 h) {
  u32 u = ((u32)h) << 16;
  return __builtin_bit_cast(float, u);
}

// ---------------- zero (uint4 grid-stride) ----------------
__global__ __launch_bounds__(256) void k_zero4(uint4* __restrict__ p, long long n4) {
  long long i = (long long)blockIdx.x * blockDim.x + threadIdx.x;
  long long stride = (long long)gridDim.x * blockDim.x;
  uint4 z; z.x = z.y = z.z = z.w = 0u;
  for (; i < n4; i += stride) p[i] = z;
}

// ---------------- f32 -> bf16 convert (x4 per thread) ----------------
__global__ __launch_bounds__(256) void k_cvt(const float* __restrict__ in,
                                             u16* __restrict__ out, long long n4) {
  long long i = (long long)blockIdx.x * blockDim.x + threadIdx.x;
  if (i >= n4) return;
  float4 v = ((const float4*)in)[i];
  u32 p0 = (u32)f32_to_bf16(v.x) | ((u32)f32_to_bf16(v.y) << 16);
  u32 p1 = (u32)f32_to_bf16(v.z) | ((u32)f32_to_bf16(v.w) << 16);
  ((u32*)out)[i * 2] = p0;
  ((u32*)out)[i * 2 + 1] = p1;
}

// ---------------- per-(dst,rel) edge counts ----------------
__global__ __launch_bounds__(256) void k_count(const int* __restrict__ dst,
                                               const int* __restrict__ rel,
                                               int* __restrict__ cnt, int E) {
  int e = blockIdx.x * blockDim.x + threadIdx.x;
  if (e < E) atomicAdd(&cnt[dst[e] * N_REL + rel[e]], 1);
}

// ---------------- scan: per-block sums ----------------
__global__ __launch_bounds__(256) void k_bsum(const int* __restrict__ cnt,
                                              int* __restrict__ bsum, int n) {
  __shared__ int sm[256];
  int i = blockIdx.x * 256 + threadIdx.x;
  int v = (i < n) ? cnt[i] : 0;
  sm[threadIdx.x] = v;
  __syncthreads();
  for (int s = 128; s > 0; s >>= 1) {
    if (threadIdx.x < s) sm[threadIdx.x] += sm[threadIdx.x + s];
    __syncthreads();
  }
  if (threadIdx.x == 0) bsum[blockIdx.x] = sm[0];
}

// ---------------- scan: single-block exclusive scan of block sums ----------------
__global__ __launch_bounds__(1024) void k_bscan(int* __restrict__ bsum, int nb) {
  __shared__ int sm[1024];
  __shared__ int carry;
  if (threadIdx.x == 0) carry = 0;
  __syncthreads();
  int niter = (nb + 1023) / 1024;
  for (int it = 0; it < niter; ++it) {
    int i = it * 1024 + threadIdx.x;
    int v = (i < nb) ? bsum[i] : 0;
    sm[threadIdx.x] = v;
    __syncthreads();
    for (int s = 1; s < 1024; s <<= 1) {
      int t = (threadIdx.x >= s) ? sm[threadIdx.x - s] : 0;
      __syncthreads();
      sm[threadIdx.x] += t;
      __syncthreads();
    }
    int incl = sm[threadIdx.x];
    int c = carry;
    __syncthreads();
    if (i < nb) bsum[i] = c + incl - v;
    if (threadIdx.x == 1023) carry = c + sm[1023];
    __syncthreads();
  }
}

// ---------------- scan: per-element exclusive offsets ----------------
__global__ __launch_bounds__(256) void k_off(const int* __restrict__ cnt,
                                             const int* __restrict__ bsum,
                                             int* __restrict__ off, int n) {
  __shared__ int sm[256];
  int i = blockIdx.x * 256 + threadIdx.x;
  int v = (i < n) ? cnt[i] : 0;
  sm[threadIdx.x] = v;
  __syncthreads();
  for (int s = 1; s < 256; s <<= 1) {
    int t = (threadIdx.x >= s) ? sm[threadIdx.x - s] : 0;
    __syncthreads();
    sm[threadIdx.x] += t;
    __syncthreads();
  }
  int excl = sm[threadIdx.x] - v + bsum[blockIdx.x];
  if (i < n) off[i] = excl;
  if (i == n - 1) off[n] = excl + v;
}

// ---------------- CSR fill (countdown — cnt is dead after k_off) ----------------
__global__ __launch_bounds__(256) void k_fill(const int* __restrict__ src,
                                              const int* __restrict__ dst,
                                              const int* __restrict__ rel,
                                              const int* __restrict__ off,
                                              int* __restrict__ cnt,
                                              int* __restrict__ bucket, int E) {
  int e = blockIdx.x * blockDim.x + threadIdx.x;
  if (e >= E) return;
  int seg = dst[e] * N_REL + rel[e];
  int old = atomicSub(&cnt[seg], 1);          // old in [1, cnt]
  bucket[off[seg] + old - 1] = src[e];
}

// ---------------- weight -> MFMA-fragment-linear bf16 ----------------
// Wf[(kb*8+t)*512 + lane*8 + j] = Bmat[k = kb*32 + (lane>>4)*8 + j][h = t*16 + (lane&15)]
// Bmat[k][h] = W[k>>7][k&127][h]  (root: nkb=4 -> k<128 -> r=0)
__global__ __launch_bounds__(256) void k_wfrag(const float* __restrict__ W,
                                               u16* __restrict__ Wf, int nkb) {
  int tid = blockIdx.x * blockDim.x + threadIdx.x;
  int total = nkb * 8 * 64;
  if (tid >= total) return;
  int lane = tid & 63;
  int t = (tid >> 6) & 7;
  int kb = tid >> 9;
  int h = t * 16 + (lane & 15);
  int kbase = kb * 32 + ((lane >> 4) << 3);
  bf16x8 frag;
#pragma unroll
  for (int j = 0; j < 8; ++j) {
    int k = kbase + j;
    frag[j] = (short)f32_to_bf16(W[(size_t)(k >> 7) * (D * D) + (size_t)(k & 127) * D + h]);
  }
  *(bf16x8*)(Wf + (size_t)tid * 8) = frag;   // tid*8 u16 = 16B aligned
}

// ---------------- fully fused RGCN layer, relation-split x4 ----------------
// One 16-node M-tile per BLOCK. The 4 waves each own 4 relations (+ 1 kb-quarter
// of the root term), gather-mean straight into A-fragment registers, MFMA vs
// frag-linear weights into private C-tiles; LDS reduce; fused bias(+ReLU)+store.
template <int L>  // L=1: bf16 out + ReLU; L=2: f32 out
__global__ __launch_bounds__(256) void k_layer(const int* __restrict__ off,
                                               const int* __restrict__ bucket,
                                               const u16* __restrict__ x,    // [N,128] bf16
                                               const u16* __restrict__ Wf,   // 64 kb frag-linear
                                               const u16* __restrict__ Rf,   // 4 kb frag-linear
                                               const float* __restrict__ bias,
                                               u16* __restrict__ outb,
                                               float* __restrict__ outf) {
  __shared__ f32x4 red[4][8][64];      // 32 KB
  int w = threadIdx.x >> 6;            // wave 0..3
  int lane = threadIdx.x & 63;
  int node0 = blockIdx.x << 4;         // 50000 = 3125*16, exact grid
  int m = lane & 15;
  int q = lane >> 4;
  int node = node0 + m;                // A-row this lane serves

  f32x4 acc[8];
#pragma unroll
  for (int t = 0; t < 8; ++t)
#pragma unroll
    for (int i = 0; i < 4; ++i) acc[t][i] = 0.0f;

  // ---- root term: this wave does kb = w ----
  {
    bf16x8 a = *(const bf16x8*)(x + ((size_t)node << 7) + w * 32 + (q << 3));
    const u16* bp = Rf + ((size_t)w << 12) + ((size_t)lane << 3);
#pragma unroll
    for (int t = 0; t < 8; ++t) {
      bf16x8 b = *(const bf16x8*)(bp + t * 512);
      acc[t] = __builtin_amdgcn_mfma_f32_16x16x32_bf16(a, b, acc[t], 0, 0, 0);
    }
  }

  // ---- 4 relations per wave: gather-mean into A-frag regs, MFMA vs W_r ----
  for (int rr = 0; rr < 4; ++rr) {
    int r = w * 4 + rr;
    int seg = (node << 4) + r;
    int o0 = off[seg];
    int o1 = off[seg + 1];

    float a0[8], a1[8], a2[8], a3[8];
#pragma unroll
    for (int j = 0; j < 8; ++j) { a0[j] = 0.f; a1[j] = 0.f; a2[j] = 0.f; a3[j] = 0.f; }

    for (int i = o0; i < o1; ++i) {    // divergent across m; exec-masked
      int s = bucket[i];
      const u16* xs = x + ((size_t)s << 7) + (q << 3);
      bf16x8 v0 = *(const bf16x8*)(xs);
      bf16x8 v1 = *(const bf16x8*)(xs + 32);
      bf16x8 v2 = *(const bf16x8*)(xs + 64);
      bf16x8 v3 = *(const bf16x8*)(xs + 96);
#pragma unroll
      for (int j = 0; j < 8; ++j) {
        a0[j] += bf16_to_f32((u16)v0[j]);
        a1[j] += bf16_to_f32((u16)v1[j]);
        a2[j] += bf16_to_f32((u16)v2[j]);
        a3[j] += bf16_to_f32((u16)v3[j]);
      }
    }

    float sc = (o1 > o0) ? 1.0f / (float)(o1 - o0) : 0.0f;
    bf16x8 f0, f1, f2, f3;
#pragma unroll
    for (int j = 0; j < 8; ++j) {
      f0[j] = (short)f32_to_bf16(a0[j] * sc);
      f1[j] = (short)f32_to_bf16(a1[j] * sc);
      f2[j] = (short)f32_to_bf16(a2[j] * sc);
      f3[j] = (short)f32_to_bf16(a3[j] * sc);
    }

    const u16* bp = Wf + ((size_t)(r * 4) << 12) + ((size_t)lane << 3);
#pragma unroll
    for (int t = 0; t < 8; ++t) {
      bf16x8 b0 = *(const bf16x8*)(bp + t * 512);
      bf16x8 b1 = *(const bf16x8*)(bp + 4096 + t * 512);
      bf16x8 b2 = *(const bf16x8*)(bp + 8192 + t * 512);
      bf16x8 b3 = *(const bf16x8*)(bp + 12288 + t * 512);
      acc[t] = __builtin_amdgcn_mfma_f32_16x16x32_bf16(f0, b0, acc[t], 0, 0, 0);
      acc[t] = __builtin_amdgcn_mfma_f32_16x16x32_bf16(f1, b1, acc[t], 0, 0, 0);
      acc[t] = __builtin_amdgcn_mfma_f32_16x16x32_bf16(f2, b2, acc[t], 0, 0, 0);
      acc[t] = __builtin_amdgcn_mfma_f32_16x16x32_bf16(f3, b3, acc[t], 0, 0, 0);
    }
  }

  // ---- LDS reduce across the 4 waves ----
#pragma unroll
  for (int t = 0; t < 8; ++t) red[w][t][lane] = acc[t];
  __syncthreads();

  // ---- epilogue: wave w handles t = 2w, 2w+1; C layout col=m, row=q*4+reg [m89] ----
#pragma unroll
  for (int j = 0; j < 2; ++j) {
    int t = w * 2 + j;
    f32x4 s0 = red[0][t][lane];
    f32x4 s1 = red[1][t][lane];
    f32x4 s2 = red[2][t][lane];
    f32x4 s3 = red[3][t][lane];
    int h = t * 16 + m;
    float bv = bias[h];
#pragma unroll
    for (int r4 = 0; r4 < 4; ++r4) {
      int n = node0 + (q << 2) + r4;
      float v = s0[r4] + s1[r4] + s2[r4] + s3[r4] + bv;
      if (L == 1) {
        v = v > 0.0f ? v : 0.0f;
        outb[(size_t)n * D + h] = f32_to_bf16(v);
      } else {
        outf[(size_t)n * D + h] = v;
      }
    }
  }
}

extern "C" void kernel_launch(void* const* d_in, const int* in_sizes, int n_in,
                              void* d_out, int out_size, void* d_ws, size_t ws_size,
                              hipStream_t stream) {
  const int* edge_index = (const int*)d_in[0];
  const int* edge_type  = (const int*)d_in[1];
  const float* emb   = (const float*)d_in[2];
  const float* W1    = (const float*)d_in[3];
  const float* root1 = (const float*)d_in[4];
  const float* b1    = (const float*)d_in[5];
  const float* W2    = (const float*)d_in[6];
  const float* root2 = (const float*)d_in[7];
  const float* b2    = (const float*)d_in[8];
  float* out = (float*)d_out;

  int E = in_sizes[0] / 2;
  const int* src = edge_index;      // row 0
  const int* dst = edge_index + E;  // row 1
  int nblocks_seg = (N_SEG + 255) / 256;  // 3125

  char* ws = (char*)d_ws;
  size_t off_b = 0;
  auto take = [&](size_t bytes) -> char* {
    char* p = ws + off_b;
    off_b += (bytes + 255) & ~(size_t)255;
    return p;
  };
  int*   cnt    = (int*)take((size_t)N_SEG * 4);
  int*   offs   = (int*)take((size_t)(N_SEG + 1) * 4);
  int*   bsum   = (int*)take((size_t)nblocks_seg * 4);
  int*   bucket = (int*)take((size_t)E * 4);
  u16*   embb   = (u16*)take((size_t)N_NODES * D * 2);
  u16*   x1     = (u16*)take((size_t)N_NODES * D * 2);
  u16*   Wf1    = (u16*)take((size_t)64 * 8 * 512 * 2);
  u16*   Rf1    = (u16*)take((size_t)4 * 8 * 512 * 2);
  u16*   Wf2    = (u16*)take((size_t)64 * 8 * 512 * 2);
  u16*   Rf2    = (u16*)take((size_t)4 * 8 * 512 * 2);
  // total ~41 MB — fits comfortably

  int eBlocks = (E + 255) / 256;
  int layerBlocks = N_NODES / 16;   // 3125 blocks, 1 tile per block

  // --- CSR build (shared by both layers) ---
  k_zero4<<<512, 256, 0, stream>>>((uint4*)cnt, (long long)N_SEG * 4 / 16);
  k_count<<<eBlocks, 256, 0, stream>>>(dst, edge_type, cnt, E);
  k_bsum<<<nblocks_seg, 256, 0, stream>>>(cnt, bsum, N_SEG);
  k_bscan<<<1, 1024, 0, stream>>>(bsum, nblocks_seg);
  k_off<<<nblocks_seg, 256, 0, stream>>>(cnt, bsum, offs, N_SEG);
  k_fill<<<eBlocks, 256, 0, stream>>>(src, dst, edge_type, offs, cnt, bucket, E);

  // --- weight prep ---
  k_cvt<<<((N_NODES * D / 4) + 255) / 256, 256, 0, stream>>>(emb, embb,
                                                             (long long)N_NODES * D / 4);
  k_wfrag<<<(64 * 8 * 64 + 255) / 256, 256, 0, stream>>>(W1, Wf1, 64);
  k_wfrag<<<(4 * 8 * 64 + 255) / 256, 256, 0, stream>>>(root1, Rf1, 4);
  k_wfrag<<<(64 * 8 * 64 + 255) / 256, 256, 0, stream>>>(W2, Wf2, 64);
  k_wfrag<<<(4 * 8 * 64 + 255) / 256, 256, 0, stream>>>(root2, Rf2, 4);

  // --- two fused layers ---
  k_layer<1><<<layerBlocks, 256, 0, stream>>>(offs, bucket, embb, Wf1, Rf1, b1,
                                              x1, nullptr);
  k_layer<2><<<layerBlocks, 256, 0, stream>>>(offs, bucket, x1, Wf2, Rf2, b2,
                                              nullptr, out);
}